// Round 4
// baseline (154.901 us; speedup 1.0000x reference)
//
#include <hip/hip_runtime.h>

#define N_PP 100000
#define N_A  50000
#define NEDGE 500000
#define BSZ 8192
#define TILE 128
#define SCALE 1.44269504088896f   // log2(e)

typedef __attribute__((ext_vector_type(8)))  short bf16x8;
typedef __attribute__((ext_vector_type(16))) float f32x16;
typedef __attribute__((ext_vector_type(4)))  float f32x4;
typedef unsigned short u16;

#if __has_builtin(__builtin_amdgcn_sqrtf)
#define FAST_SQRT(x) __builtin_amdgcn_sqrtf(x)
#else
#define FAST_SQRT(x) sqrtf(x)
#endif
#if __has_builtin(__builtin_amdgcn_exp2f)
#define FAST_EXP2(x) __builtin_amdgcn_exp2f(x)
#else
#define FAST_EXP2(x) exp2f(x)
#endif

__device__ __forceinline__ u16 f2bf(float f) {
    unsigned u = __builtin_bit_cast(unsigned, f);
    u += 0x7FFFu + ((u >> 16) & 1u);     // round-to-nearest-even
    return (u16)(u >> 16);
}
__device__ __forceinline__ float bf2f(u16 s) {
    unsigned u = ((unsigned)s) << 16;
    return __builtin_bit_cast(float, u);
}

__device__ __forceinline__ bf16x8 load_frag_f32(const float* __restrict__ src) {
    float4 v0 = *(const float4*)src;
    float4 v1 = *(const float4*)(src + 4);
    bf16x8 f;
    f[0] = (short)f2bf(v0.x); f[1] = (short)f2bf(v0.y);
    f[2] = (short)f2bf(v0.z); f[3] = (short)f2bf(v0.w);
    f[4] = (short)f2bf(v1.x); f[5] = (short)f2bf(v1.y);
    f[6] = (short)f2bf(v1.z); f[7] = (short)f2bf(v1.w);
    return f;
}

__device__ __forceinline__ float pdist16_f32(const float* __restrict__ xv,
                                             const float* __restrict__ yv) {
    float d2 = 1e-12f;
#pragma unroll
    for (int c = 0; c < 16; c += 4) {
        float4 xq = *(const float4*)(xv + c);
        float4 yq = *(const float4*)(yv + c);
        float dx = xq.x - yq.x; d2 = fmaf(dx, dx, d2);
        float dy = xq.y - yq.y; d2 = fmaf(dy, dy, d2);
        float dz = xq.z - yq.z; d2 = fmaf(dz, dz, d2);
        float dw = xq.w - yq.w; d2 = fmaf(dw, dw, d2);
    }
    return sqrtf(d2);
}

__device__ __forceinline__ float pdist16_bf(const u16* __restrict__ xr,
                                            const u16* __restrict__ yr) {
    bf16x8 x0 = *(const bf16x8*)xr,       x1 = *(const bf16x8*)(xr + 8);
    bf16x8 y0 = *(const bf16x8*)yr,       y1 = *(const bf16x8*)(yr + 8);
    float d2 = 1e-12f;
#pragma unroll
    for (int i = 0; i < 8; ++i) {
        float dx = bf2f((u16)x0[i]) - bf2f((u16)y0[i]); d2 = fmaf(dx, dx, d2);
        float dy = bf2f((u16)x1[i]) - bf2f((u16)y1[i]); d2 = fmaf(dy, dy, d2);
    }
    return sqrtf(d2);
}

__device__ __forceinline__ float block_reduce_sum_256(float v, float* red) {
#pragma unroll
    for (int o = 32; o > 0; o >>= 1) v += __shfl_down(v, o, 64);
    __syncthreads();
    if ((threadIdx.x & 63) == 0) red[threadIdx.x >> 6] = v;
    __syncthreads();
    return red[0] + red[1] + red[2] + red[3];
}

// ---------------- prep: bf16 tables + packed batch + stats ----------------
__global__ __launch_bounds__(256) void prep_kernel(
        const float* __restrict__ p, const float* __restrict__ p_star,
        const float* __restrict__ a, const float* __restrict__ beta,
        const float* __restrict__ gamma,
        const int* __restrict__ psn, const int* __restrict__ pn,
        const int* __restrict__ an,
        u16* __restrict__ ps_tab, u16* __restrict__ p_tab, u16* __restrict__ a_tab,
        u16* __restrict__ Xb, u16* __restrict__ Yp, u16* __restrict__ Ya,
        float* __restrict__ Xxx, float* __restrict__ Xg,
        float* __restrict__ Pyy, float* __restrict__ Pg,
        float* __restrict__ Ayy, float* __restrict__ Ag)
{
    const int i = blockIdx.x * 256 + threadIdx.x;
    if (i < 250000) {
        // full-table fp32 -> bf16 row conversion
        const float* src; u16* dst;
        if (i < 100000)      { src = p_star + (size_t)i * 16;            dst = ps_tab + (size_t)i * 16; }
        else if (i < 200000) { src = p + (size_t)(i - 100000) * 16;      dst = p_tab + (size_t)(i - 100000) * 16; }
        else                 { src = a + (size_t)(i - 200000) * 16;      dst = a_tab + (size_t)(i - 200000) * 16; }
        bf16x8 lo = load_frag_f32(src);
        bf16x8 hi = load_frag_f32(src + 8);
        *(bf16x8*)dst = lo;
        *(bf16x8*)(dst + 8) = hi;
    } else if (i < 250000 + 3 * BSZ) {
        const int j = i - 250000;
        const int which = j >> 13;          // 0: p_star batch, 1: p batch, 2: a batch
        const int r = j & (BSZ - 1);
        const float* src; float wsc; u16* drow; float* xxp; float* gp;
        if (which == 0) {
            int node = psn[r]; src = p_star + (size_t)node * 16;
            wsc = gamma[node] * SCALE; drow = Xb + (size_t)r * 16; xxp = Xxx; gp = Xg;
        } else if (which == 1) {
            int node = pn[r]; src = p + (size_t)node * 16;
            wsc = gamma[node + N_PP] * SCALE; drow = Yp + (size_t)r * 16; xxp = Pyy; gp = Pg;
        } else {
            int node = an[r]; src = a + (size_t)(node - N_PP) * 16;
            wsc = beta[node] * SCALE; drow = Ya + (size_t)r * 16; xxp = Ayy; gp = Ag;
        }
        bf16x8 lo = load_frag_f32(src);
        bf16x8 hi = load_frag_f32(src + 8);
        *(bf16x8*)drow = lo;
        *(bf16x8*)(drow + 8) = hi;
        float ss = 0.f;
#pragma unroll
        for (int c = 0; c < 8; ++c) {
            float q0 = bf2f((u16)lo[c]); ss = fmaf(q0, q0, ss);
            float q1 = bf2f((u16)hi[c]); ss = fmaf(q1, q1, ss);
        }
        xxp[r] = ss;
        gp[r] = wsc;
    }
}

// epilogue over one row-tile (32 rows) x two col-tiles, 16 regs per acc
template <bool DIAG>
__device__ __forceinline__ float epi_rt(
        const f32x16& ca, const f32x16& cb,
        const float* __restrict__ xxs, const float* __restrict__ gxs,
        int rb, float yy0, float gy0, float yy1, float gy1,
        int cj0, int cj1)
{
    f32x4 xxq[4], gxq[4];
#pragma unroll
    for (int q = 0; q < 4; ++q) {
        xxq[q] = *(const f32x4*)&xxs[rb + q * 8];
        gxq[q] = *(const f32x4*)&gxs[rb + q * 8];
    }
    float s = 0.f;
#pragma unroll
    for (int q = 0; q < 4; ++q) {
#pragma unroll
        for (int j = 0; j < 4; ++j) {
            const int reg = q * 4 + j;
            float sxy = xxq[q][j];
            float gx  = gxq[q][j];
            float sq0 = fmaf(-2.f, ca[reg], sxy + yy0);
            float d0  = FAST_SQRT(fmaxf(sq0, 1e-12f));
            float v0  = FAST_EXP2(fmaf(-SCALE, d0, gx + gy0));
            float sq1 = fmaf(-2.f, cb[reg], sxy + yy1);
            float d1  = FAST_SQRT(fmaxf(sq1, 1e-12f));
            float v1  = FAST_EXP2(fmaf(-SCALE, d1, gx + gy1));
            if (DIAG) {
                int row = rb + q * 8 + j;
                v0 = (cj0 > row) ? v0 : 0.f;
                v1 = (cj1 > row) ? v1 : 0.f;
            }
            s += v0 + v1;
        }
    }
    return s;
}

template <bool PACKED>
__global__ __launch_bounds__(256) void fused_kernel(
        const float* __restrict__ p, const float* __restrict__ p_star,
        const float* __restrict__ a, const float* __restrict__ beta,
        const float* __restrict__ gamma,
        const int* __restrict__ edges_pp, const int* __restrict__ edges_ap,
        const int* __restrict__ psn, const int* __restrict__ pn,
        const int* __restrict__ an,
        const u16* __restrict__ ps_tab, const u16* __restrict__ p_tab,
        const u16* __restrict__ a_tab,
        const u16* __restrict__ Xb, const u16* __restrict__ Yp,
        const u16* __restrict__ Ya,
        const float* __restrict__ Xxx, const float* __restrict__ Xg,
        const float* __restrict__ Pyy, const float* __restrict__ Pg,
        const float* __restrict__ Ayy, const float* __restrict__ Ag,
        double* __restrict__ acc)
{
    __shared__ float xxs[TILE], gxs[TILE], yys[TILE], gys[TILE];
    __shared__ float red[4];

    const int bx = blockIdx.x, by = blockIdx.y, z = blockIdx.z;
    const int t = threadIdx.x;

    if (z == 0 && bx < by) {
        // ---------- repurposed idle blocks: edge (link) terms ----------
        int u = (by * (by - 1)) / 2 + bx;      // 0 .. 2015
        int i = u * 256 + t;                   // 0 .. 516095
        float tpp = 0.f, tap = 0.f;
        if (i < NEDGE) {
            int e0 = edges_pp[i], e1 = edges_pp[NEDGE + i];
            int f0 = edges_ap[i], f1 = edges_ap[NEDGE + i];
            if (PACKED) {
                tpp = gamma[e0] + gamma[e1 + N_PP]
                    - pdist16_bf(ps_tab + (size_t)e0 * 16, p_tab + (size_t)e1 * 16);
                tap = beta[f0] + beta[f1]
                    - pdist16_bf(ps_tab + (size_t)f0 * 16, a_tab + (size_t)(f1 - N_PP) * 16);
            } else {
                tpp = gamma[e0] + gamma[e1 + N_PP]
                    - pdist16_f32(p_star + (size_t)e0 * 16, p + (size_t)e1 * 16);
                tap = beta[f0] + beta[f1]
                    - pdist16_f32(p_star + (size_t)f0 * 16, a + (size_t)(f1 - N_PP) * 16);
            }
        }
        float s0 = block_reduce_sum_256(tpp, red);
        if (t == 0) atomicAdd(acc + 0, (double)s0);
        float s1 = block_reduce_sum_256(tap, red);
        if (t == 0) atomicAdd(acc + 2, (double)s1);
        return;
    }

    // ---------- pairwise (non-link) blocks ----------
    const bool pp   = (z == 0);
    const bool diag = pp && (bx == by);
    double* accp    = acc + (pp ? 1 : 3);

    const int l  = t & 63, w = t >> 6;
    const int wr = w >> 1, wc = w & 1;  // wave -> 64x64 sub-tile
    const int l31 = l & 31, h = l >> 5; // MFMA lane decomposition

    bf16x8 aF0, aF1, bF0, bF1;
    if (PACKED) {
        const u16* Ytab = pp ? Yp : Ya;
        const int ar0 = by * TILE + wr * 64 + l31;
        const int bc0 = bx * TILE + wc * 64 + l31;
        aF0 = *(const bf16x8*)(Xb   + (size_t)ar0 * 16 + h * 8);
        aF1 = *(const bf16x8*)(Xb   + (size_t)(ar0 + 32) * 16 + h * 8);
        bF0 = *(const bf16x8*)(Ytab + (size_t)bc0 * 16 + h * 8);
        bF1 = *(const bf16x8*)(Ytab + (size_t)(bc0 + 32) * 16 + h * 8);
        if (t < 128) {
            xxs[t] = Xxx[by * TILE + t];
            gxs[t] = Xg[by * TILE + t];
        } else {
            const int r = t - 128;
            const float* yyp = pp ? Pyy : Ayy;
            const float* gyp = pp ? Pg : Ag;
            yys[r] = yyp[bx * TILE + r];
            gys[r] = gyp[bx * TILE + r];
        }
    } else {
        const float* Y  = pp ? p : a;
        const float* wv = pp ? gamma : beta;
        const int* yn   = pp ? pn : an;
        const int wyo   = pp ? N_PP : 0;
        const int yvo   = pp ? 0 : -N_PP;
        const int ar0 = by * TILE + wr * 64 + l31;
        const int an0 = psn[ar0], an1 = psn[ar0 + 32];
        aF0 = load_frag_f32(p_star + (size_t)an0 * 16 + h * 8);
        aF1 = load_frag_f32(p_star + (size_t)an1 * 16 + h * 8);
        const int bc0 = bx * TILE + wc * 64 + l31;
        const int bn0 = yn[bc0], bn1 = yn[bc0 + 32];
        bF0 = load_frag_f32(Y + (size_t)(bn0 + yvo) * 16 + h * 8);
        bF1 = load_frag_f32(Y + (size_t)(bn1 + yvo) * 16 + h * 8);
        const bool isx = (t < 128);
        const int  r   = isx ? t : t - 128;
        const int  node = isx ? psn[by * TILE + r] : yn[bx * TILE + r];
        const float* src = isx ? (p_star + (size_t)node * 16)
                               : (Y + (size_t)(node + yvo) * 16);
        float ss = 0.f;
#pragma unroll
        for (int c = 0; c < 16; c += 4) {
            float4 v = *(const float4*)(src + c);
            float q0 = bf2f(f2bf(v.x)), q1 = bf2f(f2bf(v.y));
            float q2 = bf2f(f2bf(v.z)), q3 = bf2f(f2bf(v.w));
            ss = fmaf(q0, q0, ss); ss = fmaf(q1, q1, ss);
            ss = fmaf(q2, q2, ss); ss = fmaf(q3, q3, ss);
        }
        if (isx) { xxs[r] = ss; gxs[r] = wv[node] * SCALE; }
        else     { yys[r] = ss; gys[r] = wv[node + wyo] * SCALE; }
    }
    __syncthreads();

    f32x16 c00, c01, c10, c11;
#pragma unroll
    for (int i = 0; i < 16; ++i) { c00[i] = 0.f; c01[i] = 0.f; c10[i] = 0.f; c11[i] = 0.f; }
    c00 = __builtin_amdgcn_mfma_f32_32x32x16_bf16(aF0, bF0, c00, 0, 0, 0);
    c01 = __builtin_amdgcn_mfma_f32_32x32x16_bf16(aF0, bF1, c01, 0, 0, 0);
    c10 = __builtin_amdgcn_mfma_f32_32x32x16_bf16(aF1, bF0, c10, 0, 0, 0);
    c11 = __builtin_amdgcn_mfma_f32_32x32x16_bf16(aF1, bF1, c11, 0, 0, 0);

    const int cj0 = wc * 64 + l31, cj1 = cj0 + 32;
    const float yy0 = yys[cj0], gy0 = gys[cj0];
    const float yy1 = yys[cj1], gy1 = gys[cj1];
    const int rb0 = wr * 64 + 4 * h;
    const int rb1 = rb0 + 32;

    float sum;
    if (diag) {
        sum = epi_rt<true >(c00, c01, xxs, gxs, rb0, yy0, gy0, yy1, gy1, cj0, cj1)
            + epi_rt<true >(c10, c11, xxs, gxs, rb1, yy0, gy0, yy1, gy1, cj0, cj1);
    } else {
        sum = epi_rt<false>(c00, c01, xxs, gxs, rb0, yy0, gy0, yy1, gy1, cj0, cj1)
            + epi_rt<false>(c10, c11, xxs, gxs, rb1, yy0, gy0, yy1, gy1, cj0, cj1);
    }

    float bs = block_reduce_sum_256(sum, red);
    if (t == 0) atomicAdd(accp, (double)bs);
}

__global__ void finalize_kernel(const double* __restrict__ acc, float* __restrict__ out)
{
    double nll_pp = -(acc[0] - acc[1]);
    double nll_ap = -(acc[2] - acc[3]);
    out[0] = (float)(0.5 * nll_pp / (double)BSZ + 0.5 * nll_ap / (double)BSZ);
}

extern "C" void kernel_launch(void* const* d_in, const int* in_sizes, int n_in,
                              void* d_out, int out_size, void* d_ws, size_t ws_size,
                              hipStream_t stream)
{
    const float* p       = (const float*)d_in[0];
    const float* p_star  = (const float*)d_in[1];
    const float* a       = (const float*)d_in[2];
    const float* beta    = (const float*)d_in[3];
    const float* gamma   = (const float*)d_in[4];
    const int* edges_pp  = (const int*)d_in[5];
    const int* edges_ap  = (const int*)d_in[6];
    const int* psn       = (const int*)d_in[7];
    const int* pn        = (const int*)d_in[8];
    const int* an        = (const int*)d_in[9];

    char* ws = (char*)d_ws;
    double* acc = (double*)ws;
    size_t off = 64;
    u16* ps_tab = (u16*)(ws + off); off += (size_t)100000 * 32;
    u16* p_tab  = (u16*)(ws + off); off += (size_t)100000 * 32;
    u16* a_tab  = (u16*)(ws + off); off += (size_t)50000 * 32;
    u16* Xb     = (u16*)(ws + off); off += (size_t)BSZ * 32;
    u16* Yp     = (u16*)(ws + off); off += (size_t)BSZ * 32;
    u16* Ya     = (u16*)(ws + off); off += (size_t)BSZ * 32;
    float* Xxx  = (float*)(ws + off); off += BSZ * 4;
    float* Xg   = (float*)(ws + off); off += BSZ * 4;
    float* Pyy  = (float*)(ws + off); off += BSZ * 4;
    float* Pg   = (float*)(ws + off); off += BSZ * 4;
    float* Ayy  = (float*)(ws + off); off += BSZ * 4;
    float* Ag   = (float*)(ws + off); off += BSZ * 4;
    const bool packed = (ws_size >= off);

    hipMemsetAsync(d_ws, 0, 64, stream);

    dim3 grid(BSZ / TILE, BSZ / TILE, 2);
    if (packed) {
        const int prep_items = 250000 + 3 * BSZ;
        prep_kernel<<<(prep_items + 255) / 256, 256, 0, stream>>>(
            p, p_star, a, beta, gamma, psn, pn, an,
            ps_tab, p_tab, a_tab, Xb, Yp, Ya, Xxx, Xg, Pyy, Pg, Ayy, Ag);
        fused_kernel<true><<<grid, 256, 0, stream>>>(
            p, p_star, a, beta, gamma, edges_pp, edges_ap, psn, pn, an,
            ps_tab, p_tab, a_tab, Xb, Yp, Ya, Xxx, Xg, Pyy, Pg, Ayy, Ag, acc);
    } else {
        fused_kernel<false><<<grid, 256, 0, stream>>>(
            p, p_star, a, beta, gamma, edges_pp, edges_ap, psn, pn, an,
            nullptr, nullptr, nullptr, nullptr, nullptr, nullptr,
            nullptr, nullptr, nullptr, nullptr, nullptr, nullptr, acc);
    }

    finalize_kernel<<<1, 1, 0, stream>>>(acc, (float*)d_out);
}

// Round 5
// 85.832 us; speedup vs baseline: 1.8047x; 1.8047x over previous
//
#include <hip/hip_runtime.h>

#define N_PP 100000
#define N_A  50000
#define NEDGE 500000
#define BSZ 8192
#define TILE 128
#define SCALE 1.44269504088896f   // log2(e)

#define GRID_F 1024               // fused kernel blocks (4 per CU)
#define PAIR_JOBS 8192            // 4096 pp (lower half skipped) + 4096 ap
#define EDGE_JOBS 489             // 489 * 1024 edges >= 500000
#define NJOBS (PAIR_JOBS + EDGE_JOBS)

typedef __attribute__((ext_vector_type(8)))  short bf16x8;
typedef __attribute__((ext_vector_type(16))) float f32x16;
typedef __attribute__((ext_vector_type(4)))  float f32x4;
typedef unsigned short u16;

#if __has_builtin(__builtin_amdgcn_sqrtf)
#define FAST_SQRT(x) __builtin_amdgcn_sqrtf(x)
#else
#define FAST_SQRT(x) sqrtf(x)
#endif
#if __has_builtin(__builtin_amdgcn_exp2f)
#define FAST_EXP2(x) __builtin_amdgcn_exp2f(x)
#else
#define FAST_EXP2(x) exp2f(x)
#endif

__device__ __forceinline__ u16 f2bf(float f) {
    unsigned u = __builtin_bit_cast(unsigned, f);
    u += 0x7FFFu + ((u >> 16) & 1u);     // round-to-nearest-even
    return (u16)(u >> 16);
}
__device__ __forceinline__ float bf2f(u16 s) {
    unsigned u = ((unsigned)s) << 16;
    return __builtin_bit_cast(float, u);
}

__device__ __forceinline__ bf16x8 load_frag_f32(const float* __restrict__ src) {
    float4 v0 = *(const float4*)src;
    float4 v1 = *(const float4*)(src + 4);
    bf16x8 f;
    f[0] = (short)f2bf(v0.x); f[1] = (short)f2bf(v0.y);
    f[2] = (short)f2bf(v0.z); f[3] = (short)f2bf(v0.w);
    f[4] = (short)f2bf(v1.x); f[5] = (short)f2bf(v1.y);
    f[6] = (short)f2bf(v1.z); f[7] = (short)f2bf(v1.w);
    return f;
}

__device__ __forceinline__ float pdist16_bf(const u16* __restrict__ xr,
                                            const u16* __restrict__ yr) {
    bf16x8 x0 = *(const bf16x8*)xr, x1 = *(const bf16x8*)(xr + 8);
    bf16x8 y0 = *(const bf16x8*)yr, y1 = *(const bf16x8*)(yr + 8);
    float d2 = 1e-12f;
#pragma unroll
    for (int i = 0; i < 8; ++i) {
        float dx = bf2f((u16)x0[i]) - bf2f((u16)y0[i]); d2 = fmaf(dx, dx, d2);
        float dy = bf2f((u16)x1[i]) - bf2f((u16)y1[i]); d2 = fmaf(dy, dy, d2);
    }
    return sqrtf(d2);
}

__device__ __forceinline__ float pdist16_f32(const float* __restrict__ xv,
                                             const float* __restrict__ yv) {
    float d2 = 1e-12f;
#pragma unroll
    for (int c = 0; c < 16; c += 4) {
        float4 xq = *(const float4*)(xv + c);
        float4 yq = *(const float4*)(yv + c);
        float dx = xq.x - yq.x; d2 = fmaf(dx, dx, d2);
        float dy = xq.y - yq.y; d2 = fmaf(dy, dy, d2);
        float dz = xq.z - yq.z; d2 = fmaf(dz, dz, d2);
        float dw = xq.w - yq.w; d2 = fmaf(dw, dw, d2);
    }
    return sqrtf(d2);
}

// ---------------- prep: bf16 tables + packed batch + stats ----------------
__global__ __launch_bounds__(256) void prep_kernel(
        const float* __restrict__ p, const float* __restrict__ p_star,
        const float* __restrict__ a, const float* __restrict__ beta,
        const float* __restrict__ gamma,
        const int* __restrict__ psn, const int* __restrict__ pn,
        const int* __restrict__ an,
        u16* __restrict__ ps_tab, u16* __restrict__ p_tab, u16* __restrict__ a_tab,
        u16* __restrict__ Xb, u16* __restrict__ Yp, u16* __restrict__ Ya,
        float* __restrict__ Xxx, float* __restrict__ Xg,
        float* __restrict__ Pyy, float* __restrict__ Pg,
        float* __restrict__ Ayy, float* __restrict__ Ag)
{
    const int NITEMS = 250000 + 3 * BSZ;
    for (int i = blockIdx.x * 256 + threadIdx.x; i < NITEMS; i += gridDim.x * 256) {
        if (i < 250000) {
            const float* src; u16* dst;
            if (i < 100000)      { src = p_star + (size_t)i * 16;       dst = ps_tab + (size_t)i * 16; }
            else if (i < 200000) { src = p + (size_t)(i - 100000) * 16; dst = p_tab + (size_t)(i - 100000) * 16; }
            else                 { src = a + (size_t)(i - 200000) * 16; dst = a_tab + (size_t)(i - 200000) * 16; }
            bf16x8 lo = load_frag_f32(src);
            bf16x8 hi = load_frag_f32(src + 8);
            *(bf16x8*)dst = lo;
            *(bf16x8*)(dst + 8) = hi;
        } else {
            const int j = i - 250000;
            const int which = j >> 13;   // 0: p_star batch, 1: p batch, 2: a batch
            const int r = j & (BSZ - 1);
            const float* src; float wsc; u16* drow; float* xxp; float* gp;
            if (which == 0) {
                int node = psn[r]; src = p_star + (size_t)node * 16;
                wsc = gamma[node] * SCALE; drow = Xb + (size_t)r * 16; xxp = Xxx; gp = Xg;
            } else if (which == 1) {
                int node = pn[r]; src = p + (size_t)node * 16;
                wsc = gamma[node + N_PP] * SCALE; drow = Yp + (size_t)r * 16; xxp = Pyy; gp = Pg;
            } else {
                int node = an[r]; src = a + (size_t)(node - N_PP) * 16;
                wsc = beta[node] * SCALE; drow = Ya + (size_t)r * 16; xxp = Ayy; gp = Ag;
            }
            bf16x8 lo = load_frag_f32(src);
            bf16x8 hi = load_frag_f32(src + 8);
            *(bf16x8*)drow = lo;
            *(bf16x8*)(drow + 8) = hi;
            float ss = 0.f;
#pragma unroll
            for (int c = 0; c < 8; ++c) {
                float q0 = bf2f((u16)lo[c]); ss = fmaf(q0, q0, ss);
                float q1 = bf2f((u16)hi[c]); ss = fmaf(q1, q1, ss);
            }
            xxp[r] = ss;
            gp[r] = wsc;
        }
    }
}

// epilogue over one row-tile (32 rows) x two col-tiles; stats from global ptrs
template <bool DIAG>
__device__ __forceinline__ float epi_rt(
        const f32x16& ca, const f32x16& cb,
        const float* __restrict__ xxg, const float* __restrict__ gxg,
        int rb, float yy0, float gy0, float yy1, float gy1,
        int cj0, int cj1)
{
    f32x4 xxq[4], gxq[4];
#pragma unroll
    for (int q = 0; q < 4; ++q) {
        xxq[q] = *(const f32x4*)&xxg[rb + q * 8];
        gxq[q] = *(const f32x4*)&gxg[rb + q * 8];
    }
    float s = 0.f;
#pragma unroll
    for (int q = 0; q < 4; ++q) {
#pragma unroll
        for (int j = 0; j < 4; ++j) {
            const int reg = q * 4 + j;
            float sxy = xxq[q][j];
            float gx  = gxq[q][j];
            float sq0 = fmaf(-2.f, ca[reg], sxy + yy0);
            float d0  = FAST_SQRT(fmaxf(sq0, 1e-12f));
            float v0  = FAST_EXP2(fmaf(-SCALE, d0, gx + gy0));
            float sq1 = fmaf(-2.f, cb[reg], sxy + yy1);
            float d1  = FAST_SQRT(fmaxf(sq1, 1e-12f));
            float v1  = FAST_EXP2(fmaf(-SCALE, d1, gx + gy1));
            if (DIAG) {
                int row = rb + q * 8 + j;
                v0 = (cj0 > row) ? v0 : 0.f;
                v1 = (cj1 > row) ? v1 : 0.f;
            }
            s += v0 + v1;
        }
    }
    return s;
}

// ---------------- fused job-loop kernel ----------------
// jobs [0,4096):          pp pair tile (bx=j&63, by=j>>6), skip bx<by
// jobs [4096,8192):       ap pair tile
// jobs [8192,8192+489):   edge chunk of 1024 edges (both modalities)
template <bool PACKED>
__global__ __launch_bounds__(256) void fused_kernel(
        const float* __restrict__ p, const float* __restrict__ p_star,
        const float* __restrict__ a, const float* __restrict__ beta,
        const float* __restrict__ gamma,
        const int* __restrict__ edges_pp, const int* __restrict__ edges_ap,
        const int* __restrict__ psn, const int* __restrict__ pn,
        const int* __restrict__ an,
        const u16* __restrict__ ps_tab, const u16* __restrict__ p_tab,
        const u16* __restrict__ a_tab,
        const u16* __restrict__ Xb, const u16* __restrict__ Yp,
        const u16* __restrict__ Ya,
        const float* __restrict__ Xxx, const float* __restrict__ Xg,
        const float* __restrict__ Pyy, const float* __restrict__ Pg,
        const float* __restrict__ Ayy, const float* __restrict__ Ag,
        float* __restrict__ partials)
{
    const int t = threadIdx.x;
    const int l = t & 63, w = t >> 6;
    const int wr = w >> 1, wc = w & 1;
    const int l31 = l & 31, h = l >> 5;

    __shared__ float sxx[TILE], sgx[TILE], syy[TILE], sgy[TILE]; // !PACKED only
    __shared__ float red4[4][4];

    float s_ppl = 0.f, s_ppn = 0.f, s_apl = 0.f, s_apn = 0.f;

    for (int j = blockIdx.x; j < NJOBS; j += gridDim.x) {
        if (j < PAIR_JOBS) {
            const bool pp = (j < 4096);
            const int jj = pp ? j : j - 4096;
            const int bx = jj & 63, by = jj >> 6;
            if (pp && bx < by) continue;           // block-uniform skip
            const bool diag = pp && (bx == by);

            bf16x8 aF0, aF1, bF0, bF1;
            const float* xxg; const float* gxg;
            float yy0, gy0, yy1, gy1;
            const int cj0 = wc * 64 + l31, cj1 = cj0 + 32;
            const int rb0 = wr * 64 + 4 * h, rb1 = rb0 + 32;

            if (PACKED) {
                const u16* Ytab = pp ? Yp : Ya;
                const float* yyP = (pp ? Pyy : Ayy) + bx * TILE;
                const float* gyP = (pp ? Pg  : Ag ) + bx * TILE;
                const int ar0 = by * TILE + wr * 64 + l31;
                const int bc0 = bx * TILE + wc * 64 + l31;
                aF0 = *(const bf16x8*)(Xb   + (size_t)ar0 * 16 + h * 8);
                aF1 = *(const bf16x8*)(Xb   + (size_t)(ar0 + 32) * 16 + h * 8);
                bF0 = *(const bf16x8*)(Ytab + (size_t)bc0 * 16 + h * 8);
                bF1 = *(const bf16x8*)(Ytab + (size_t)(bc0 + 32) * 16 + h * 8);
                xxg = Xxx + by * TILE;
                gxg = Xg  + by * TILE;
                yy0 = yyP[cj0]; gy0 = gyP[cj0];
                yy1 = yyP[cj1]; gy1 = gyP[cj1];
            } else {
                const float* Y  = pp ? p : a;
                const float* wv = pp ? gamma : beta;
                const int* yn   = pp ? pn : an;
                const int wyo   = pp ? N_PP : 0;
                const int yvo   = pp ? 0 : -N_PP;
                const int ar0 = by * TILE + wr * 64 + l31;
                const int an0 = psn[ar0], an1 = psn[ar0 + 32];
                aF0 = load_frag_f32(p_star + (size_t)an0 * 16 + h * 8);
                aF1 = load_frag_f32(p_star + (size_t)an1 * 16 + h * 8);
                const int bc0g = bx * TILE + wc * 64 + l31;
                const int bn0 = yn[bc0g], bn1 = yn[bc0g + 32];
                bF0 = load_frag_f32(Y + (size_t)(bn0 + yvo) * 16 + h * 8);
                bF1 = load_frag_f32(Y + (size_t)(bn1 + yvo) * 16 + h * 8);
                {
                    const bool isx = (t < 128);
                    const int  r   = isx ? t : t - 128;
                    const int  node = isx ? psn[by * TILE + r] : yn[bx * TILE + r];
                    const float* src = isx ? (p_star + (size_t)node * 16)
                                           : (Y + (size_t)(node + yvo) * 16);
                    float ss = 0.f;
#pragma unroll
                    for (int c = 0; c < 16; c += 4) {
                        float4 v = *(const float4*)(src + c);
                        float q0 = bf2f(f2bf(v.x)), q1 = bf2f(f2bf(v.y));
                        float q2 = bf2f(f2bf(v.z)), q3 = bf2f(f2bf(v.w));
                        ss = fmaf(q0, q0, ss); ss = fmaf(q1, q1, ss);
                        ss = fmaf(q2, q2, ss); ss = fmaf(q3, q3, ss);
                    }
                    if (isx) { sxx[r] = ss; sgx[r] = wv[node] * SCALE; }
                    else     { syy[r] = ss; sgy[r] = wv[node + wyo] * SCALE; }
                }
                __syncthreads();
                xxg = sxx; gxg = sgx;
                yy0 = syy[cj0]; gy0 = sgy[cj0];
                yy1 = syy[cj1]; gy1 = sgy[cj1];
            }

            f32x16 c00, c01, c10, c11;
#pragma unroll
            for (int i = 0; i < 16; ++i) { c00[i] = 0.f; c01[i] = 0.f; c10[i] = 0.f; c11[i] = 0.f; }
            c00 = __builtin_amdgcn_mfma_f32_32x32x16_bf16(aF0, bF0, c00, 0, 0, 0);
            c01 = __builtin_amdgcn_mfma_f32_32x32x16_bf16(aF0, bF1, c01, 0, 0, 0);
            c10 = __builtin_amdgcn_mfma_f32_32x32x16_bf16(aF1, bF0, c10, 0, 0, 0);
            c11 = __builtin_amdgcn_mfma_f32_32x32x16_bf16(aF1, bF1, c11, 0, 0, 0);

            float sum;
            if (diag) {
                sum = epi_rt<true >(c00, c01, xxg, gxg, rb0, yy0, gy0, yy1, gy1, cj0, cj1)
                    + epi_rt<true >(c10, c11, xxg, gxg, rb1, yy0, gy0, yy1, gy1, cj0, cj1);
            } else {
                sum = epi_rt<false>(c00, c01, xxg, gxg, rb0, yy0, gy0, yy1, gy1, cj0, cj1)
                    + epi_rt<false>(c10, c11, xxg, gxg, rb1, yy0, gy0, yy1, gy1, cj0, cj1);
            }
            if (pp) s_ppn += sum; else s_apn += sum;
            if (!PACKED) __syncthreads();   // protect LDS stats reuse
        } else {
            const int base = (j - PAIR_JOBS) * 1024;
#pragma unroll 2
            for (int k = 0; k < 4; ++k) {
                int i = base + k * 256 + t;
                if (i < NEDGE) {
                    int e0 = edges_pp[i], e1 = edges_pp[NEDGE + i];
                    int f0 = edges_ap[i], f1 = edges_ap[NEDGE + i];
                    if (PACKED) {
                        s_ppl += gamma[e0] + gamma[e1 + N_PP]
                               - pdist16_bf(ps_tab + (size_t)e0 * 16, p_tab + (size_t)e1 * 16);
                        s_apl += beta[f0] + beta[f1]
                               - pdist16_bf(ps_tab + (size_t)f0 * 16, a_tab + (size_t)(f1 - N_PP) * 16);
                    } else {
                        s_ppl += gamma[e0] + gamma[e1 + N_PP]
                               - pdist16_f32(p_star + (size_t)e0 * 16, p + (size_t)e1 * 16);
                        s_apl += beta[f0] + beta[f1]
                               - pdist16_f32(p_star + (size_t)f0 * 16, a + (size_t)(f1 - N_PP) * 16);
                    }
                }
            }
        }
    }

    // ---- one block reduction at the very end: 4 categories ----
    float v4[4] = {s_ppl, s_ppn, s_apl, s_apn};
#pragma unroll
    for (int c = 0; c < 4; ++c) {
        float r = v4[c];
#pragma unroll
        for (int o = 32; o > 0; o >>= 1) r += __shfl_down(r, o, 64);
        if (l == 0) red4[w][c] = r;
    }
    __syncthreads();
    if (t < 4)
        partials[(size_t)blockIdx.x * 4 + t] =
            red4[0][t] + red4[1][t] + red4[2][t] + red4[3][t];
}

// ---------------- finalize: fp64 reduce of per-block partials ----------------
__global__ __launch_bounds__(256) void finalize_kernel(
        const float* __restrict__ partials, float* __restrict__ out)
{
    __shared__ double acc4[4];
    const int t = threadIdx.x;
    const int c = t >> 6, l = t & 63;
    double s = 0.0;
    for (int i = l; i < GRID_F; i += 64) s += (double)partials[(size_t)i * 4 + c];
#pragma unroll
    for (int o = 32; o > 0; o >>= 1) s += __shfl_down(s, o, 64);
    if (l == 0) acc4[c] = s;
    __syncthreads();
    if (t == 0) {
        double nll_pp = -(acc4[0] - acc4[1]);
        double nll_ap = -(acc4[2] - acc4[3]);
        out[0] = (float)(0.5 * nll_pp / (double)BSZ + 0.5 * nll_ap / (double)BSZ);
    }
}

extern "C" void kernel_launch(void* const* d_in, const int* in_sizes, int n_in,
                              void* d_out, int out_size, void* d_ws, size_t ws_size,
                              hipStream_t stream)
{
    const float* p       = (const float*)d_in[0];
    const float* p_star  = (const float*)d_in[1];
    const float* a       = (const float*)d_in[2];
    const float* beta    = (const float*)d_in[3];
    const float* gamma   = (const float*)d_in[4];
    const int* edges_pp  = (const int*)d_in[5];
    const int* edges_ap  = (const int*)d_in[6];
    const int* psn       = (const int*)d_in[7];
    const int* pn        = (const int*)d_in[8];
    const int* an        = (const int*)d_in[9];

    char* ws = (char*)d_ws;
    size_t off = 0;
    float* partials = (float*)(ws + off); off += (size_t)GRID_F * 4 * sizeof(float);
    u16* ps_tab = (u16*)(ws + off); off += (size_t)100000 * 32;
    u16* p_tab  = (u16*)(ws + off); off += (size_t)100000 * 32;
    u16* a_tab  = (u16*)(ws + off); off += (size_t)50000 * 32;
    u16* Xb     = (u16*)(ws + off); off += (size_t)BSZ * 32;
    u16* Yp     = (u16*)(ws + off); off += (size_t)BSZ * 32;
    u16* Ya     = (u16*)(ws + off); off += (size_t)BSZ * 32;
    float* Xxx  = (float*)(ws + off); off += BSZ * 4;
    float* Xg   = (float*)(ws + off); off += BSZ * 4;
    float* Pyy  = (float*)(ws + off); off += BSZ * 4;
    float* Pg   = (float*)(ws + off); off += BSZ * 4;
    float* Ayy  = (float*)(ws + off); off += BSZ * 4;
    float* Ag   = (float*)(ws + off); off += BSZ * 4;
    const bool packed = (ws_size >= off);

    if (packed) {
        prep_kernel<<<256, 256, 0, stream>>>(
            p, p_star, a, beta, gamma, psn, pn, an,
            ps_tab, p_tab, a_tab, Xb, Yp, Ya, Xxx, Xg, Pyy, Pg, Ayy, Ag);
        fused_kernel<true><<<GRID_F, 256, 0, stream>>>(
            p, p_star, a, beta, gamma, edges_pp, edges_ap, psn, pn, an,
            ps_tab, p_tab, a_tab, Xb, Yp, Ya, Xxx, Xg, Pyy, Pg, Ayy, Ag, partials);
    } else {
        fused_kernel<false><<<GRID_F, 256, 0, stream>>>(
            p, p_star, a, beta, gamma, edges_pp, edges_ap, psn, pn, an,
            nullptr, nullptr, nullptr, nullptr, nullptr, nullptr,
            nullptr, nullptr, nullptr, nullptr, nullptr, nullptr, partials);
    }

    finalize_kernel<<<1, 256, 0, stream>>>(partials, (float*)d_out);
}